// Round 20
// baseline (228.674 us; speedup 1.0000x reference)
//
#include <hip/hip_runtime.h>
#include <hip/hip_bf16.h>

typedef float f32x4 __attribute__((ext_vector_type(4)));
typedef short bf16x8 __attribute__((ext_vector_type(8)));
typedef unsigned short ushort8 __attribute__((ext_vector_type(8)));
typedef unsigned int uint2v __attribute__((ext_vector_type(2)));

__device__ __forceinline__ unsigned short f2bf(float f) {
    union { float f; unsigned u; } v; v.f = f;
    unsigned r = v.u + 0x7fffu + ((v.u >> 16) & 1u);
    return (unsigned short)(r >> 16);
}

// official HIP bf16 conversion (RNE, HW cvt) — used in k_attn epilogue
__device__ __forceinline__ unsigned short f2bf_hw(float f) {
    union { __hip_bfloat16 b; unsigned short u; } cv;
    cv.b = __float2bfloat16(f);
    return cv.u;
}

#define GLDS16(g, l)                                                        \
    __builtin_amdgcn_global_load_lds(                                       \
        (const __attribute__((address_space(1))) unsigned int*)(const void*)(g), \
        (__attribute__((address_space(3))) unsigned int*)(void*)(l), 16, 0, 0)

// ------------- fused prep: x fp32->bf16 + both weight transposes -------
__global__ __launch_bounds__(256) void k_prep(const float* __restrict__ x,
                                              unsigned short* __restrict__ xb,
                                              const float* __restrict__ wq,
                                              unsigned short* __restrict__ wqt,
                                              const float* __restrict__ wp,
                                              unsigned short* __restrict__ wpt) {
    __shared__ float t[32][33];
    int bid = blockIdx.x, tid = threadIdx.x;
    if (bid < 4096) {
        int i = bid * 256 + tid;
        float4 a = ((const float4*)x)[i * 2];
        float4 b = ((const float4*)x)[i * 2 + 1];
        ushort8 o = { f2bf(a.x), f2bf(a.y), f2bf(a.z), f2bf(a.w),
                      f2bf(b.x), f2bf(b.y), f2bf(b.z), f2bf(b.w) };
        ((ushort8*)xb)[i] = o;
        return;
    }
    const float* in; unsigned short* out; int C, c0, r0;
    const int R = 1024;
    if (bid < 7168) {
        int bx = bid - 4096; in = wq; out = wqt; C = 3072;
        c0 = (bx % 96) * 32; r0 = (bx / 96) * 32;
    } else {
        int bx = bid - 7168; in = wp; out = wpt; C = 1024;
        c0 = (bx & 31) * 32; r0 = (bx >> 5) * 32;
    }
    int tx = tid & 31, ty = tid >> 5;
#pragma unroll
    for (int i = 0; i < 4; i++)
        t[ty + i * 8][tx] = in[(size_t)(r0 + ty + i * 8) * C + c0 + tx];
    __syncthreads();
#pragma unroll
    for (int i = 0; i < 4; i++)
        out[(size_t)(c0 + ty + i * 8) * R + r0 + tx] = f2bf(t[tx][ty + i * 8]);
}

// ---------------- GEMM: C[M,N] = A[M,K](bf16) * Bt[N,K](bf16)^T --------
// r19-VERIFIED: double-buffered GLDS prefetch, BK=32, ONE barrier/K-step.
// MODE 0: out fp32 row-major + bias.
// MODE 1: QKV scatter: Q (x0.125)/K direct; V via two-pass LDS transpose.
template <int MODE>
__global__ __launch_bounds__(256)
void k_gemm(const unsigned short* __restrict__ A, const unsigned short* __restrict__ Bt,
            const float* __restrict__ bias, int M, int N, int K,
            float* __restrict__ outF, unsigned short* __restrict__ q_ws,
            unsigned short* __restrict__ k_ws, unsigned short* __restrict__ vt_ws) {
    __shared__ __attribute__((aligned(16))) unsigned short SMEM[16384];  // 32 KB
    int tid = threadIdx.x;
    int lane = tid & 63, w = tid >> 6;
    int wr = w >> 1, wc = w & 1;

    // T1 XCD-aware chunked swizzle (bijective: grid counts are multiples of 8)
    int nbx = gridDim.x;
    int flat = blockIdx.y * nbx + blockIdx.x;
    int cpx = (nbx * gridDim.y) >> 3;
    int wg = (flat & 7) * cpx + (flat >> 3);
    int m0 = (wg / nbx) * 128, n0 = (wg % nbx) * 128;

    f32x4 acc[4][4] = {};

    int srow = tid >> 2, sk = (tid & 3) * 8;
    const unsigned short* aS0 = A + (size_t)(m0 + srow) * K + sk;
    const unsigned short* aS1 = A + (size_t)(m0 + 64 + srow) * K + sk;
    const unsigned short* bS0 = Bt + (size_t)(n0 + srow) * K + sk;
    const unsigned short* bS1 = Bt + (size_t)(n0 + 64 + srow) * K + sk;
    int wb = w * 512;   // wave-uniform dest base (shorts)

    int ko = (lane >> 4) * 8;
    int l15g = lane & 15;
    int arow = (wr * 64 + l15g) * 32;
    int brow = (wc * 64 + l15g) * 32;

#define GSTAGE(BUF)                                                            \
    {                                                                          \
        GLDS16(aS0, SMEM + (BUF) * 4096 + wb);                                 \
        GLDS16(aS1, SMEM + (BUF) * 4096 + 2048 + wb);                          \
        GLDS16(bS0, SMEM + 8192 + (BUF) * 4096 + wb);                          \
        GLDS16(bS1, SMEM + 8192 + (BUF) * 4096 + 2048 + wb);                   \
        aS0 += 32; aS1 += 32; bS0 += 32; bS1 += 32;                            \
    }

    GSTAGE(0);
    __syncthreads();   // prologue: tile 0 landed

    int nt = K >> 5;
    for (int t = 0; t < nt; t++) {
        int cur = t & 1;
        if (t + 1 < nt) GSTAGE(cur ^ 1);   // DMA next tile; overlaps compute
        const unsigned short* Ab = SMEM + cur * 4096;
        const unsigned short* Bb = SMEM + 8192 + cur * 4096;
        bf16x8 af[4], bfr[4];
#pragma unroll
        for (int i = 0; i < 4; i++) {
            af[i]  = *(const bf16x8*)&Ab[arow + i * 512 + ko];
            bfr[i] = *(const bf16x8*)&Bb[brow + i * 512 + ko];
        }
#pragma unroll
        for (int i = 0; i < 4; i++)
#pragma unroll
            for (int j = 0; j < 4; j++)
                acc[i][j] = __builtin_amdgcn_mfma_f32_16x16x32_bf16(af[i], bfr[j], acc[i][j], 0, 0, 0);
        __syncthreads();   // reads done + next-tile DMA landed
    }
#undef GSTAGE

    int colBase = n0 + wc * 64 + l15g;
    int rowBase = m0 + wr * 64 + ((lane >> 4) << 2);

    if constexpr (MODE == 1) {
        if (n0 >= 2048) {
            // ---- V: two-pass transpose via LDS [64][136] (aliases staging) ----
            unsigned short* Vt = SMEM;
            int rowrd = tid >> 2;
#pragma unroll
            for (int pass = 0; pass < 2; pass++) {
                __syncthreads();   // prior reads (staging / pass-0 stores) done
                if (wc == pass) {
#pragma unroll
                    for (int i = 0; i < 4; i++)
#pragma unroll
                        for (int j = 0; j < 4; j++)
#pragma unroll
                            for (int r = 0; r < 4; r++) {
                                int nl = j * 16 + l15g;                   // 0..63
                                int ml = wr * 64 + i * 16 + ((lane >> 4) << 2) + r;
                                Vt[nl * 136 + ml] = f2bf(acc[i][j][r] + bias[n0 + pass * 64 + nl]);
                            }
                }
                __syncthreads();
                int rem = (n0 + pass * 64 + rowrd) & 1023;
                unsigned short* dst = vt_ws
                    + ((size_t)((m0 >> 11) * 16 + (rem >> 6)) * 64 + (rem & 63)) * 2048
                    + (m0 & 2047) + (tid & 3) * 32;
                const unsigned short* src = &Vt[rowrd * 136 + (tid & 3) * 32];
#pragma unroll
                for (int q2 = 0; q2 < 4; q2++)
                    ((uint4*)dst)[q2] = ((const uint4*)src)[q2];
            }
            return;
        }
    }

#pragma unroll
    for (int i = 0; i < 4; i++)
#pragma unroll
        for (int j = 0; j < 4; j++)
#pragma unroll
            for (int r = 0; r < 4; r++) {
                int m = rowBase + i * 16 + r;
                int n = colBase + j * 16;
                float v = acc[i][j][r] + bias[n];
                if constexpr (MODE == 0) {
                    outF[(size_t)m * N + n] = v;
                } else {
                    int which = n >> 10, rem = n & 1023;
                    int h = rem >> 6, d = rem & 63;
                    int b = m >> 11, s = m & 2047;
                    int bh = b * 16 + h;
                    if (which == 0)
                        q_ws[((size_t)bh * 2048 + s) * 64 + d] = f2bf(v * 0.125f);
                    else
                        k_ws[((size_t)bh * 2048 + s) * 64 + d] = f2bf(v);
                }
            }
}

// ---------------- flash attention: per (bh, 256 q-rows) ----------------
// r17/r18/r19-verified compute patterns; r20 delta: QBLK=64/wave (4 halves),
// grid 512 (tail-free 2 blocks/CU). K/V ds_reads amortized over 2x q-rows,
// barrier/fence count per q-row halved. Mechanical half<2 -> half<4
// extension of the r7-verified QBLK 16->32 move; staging/swizzle/fence
// byte-identical. LDS 69632B (gfx950 allows >64KB/WG).
__global__ __launch_bounds__(256)
void k_attn(const unsigned short* __restrict__ q_ws, const unsigned short* __restrict__ k_ws,
            const unsigned short* __restrict__ vt_ws, unsigned short* __restrict__ o_ws) {
    __shared__ __attribute__((aligned(16))) unsigned short Ksh[2][64 * 64];
    __shared__ __attribute__((aligned(16))) unsigned short Vsh[2][64 * 64];
    __shared__ __attribute__((aligned(16))) unsigned short Psh[256 * 72];
    int tid = threadIdx.x, lane = tid & 63, w = tid >> 6;
    int l15 = lane & 15, g = lane >> 4;

    // T1 swizzle: flat 512 blocks -> XCD chunks of 64 (8 bh per XCD)
    int flat = blockIdx.y * 8 + blockIdx.x;
    int wg = (flat & 7) * 64 + (flat >> 3);
    int bh = wg >> 3;
    int q0 = (wg & 7) * 256;
    int b = bh >> 4, h = bh & 15;

    const unsigned short* qp = q_ws + (size_t)bh * 2048 * 64;
    const unsigned short* kp = k_ws + (size_t)bh * 2048 * 64;
    const unsigned short* vp = vt_ws + (size_t)bh * 64 * 2048;

    int ko = g * 8;
    // Q fragments (A-operand): rows q = q0 + w*64 + half*16 + l15
    bf16x8 qf[4][2];
#pragma unroll
    for (int half = 0; half < 4; half++) {
        const unsigned short* qr = qp + (size_t)(q0 + w * 64 + half * 16 + l15) * 64;
        qf[half][0] = *(const bf16x8*)(qr + ko);
        qf[half][1] = *(const bf16x8*)(qr + 32 + ko);
    }

    f32x4 oacc[4][4] = {};
    float lacc[4][4] = {};

    // GLDS staging geometry: swizzle + K row-perm applied to SOURCE address
    int srow8 = tid >> 3;                       // 0..31
    int scol = ((tid & 7) ^ (srow8 & 7)) * 8;   // XOR-swizzled source chunk
    int kv0 = (srow8 & 15) * 4 + (srow8 >> 4);  // K row-perm for phys row srow8
    const unsigned short* kN0 = kp + (size_t)kv0 * 64 + scol;
    const unsigned short* kN1 = kp + (size_t)(kv0 + 2) * 64 + scol;
    const unsigned short* vN0 = vp + (size_t)srow8 * 2048 + scol;
    const unsigned short* vN1 = vp + (size_t)(srow8 + 32) * 2048 + scol;

#define STAGE(BUF)                                                             \
    {                                                                          \
        GLDS16(kN0, &Ksh[BUF][w * 512]);                                       \
        GLDS16(kN1, &Ksh[BUF][2048 + w * 512]);                                \
        GLDS16(vN0, &Vsh[BUF][w * 512]);                                       \
        GLDS16(vN1, &Vsh[BUF][2048 + w * 512]);                                \
        kN0 += 4096; kN1 += 4096; vN0 += 64; vN1 += 64;                        \
    }

    STAGE(0);
    __syncthreads();   // prologue DMA landed (vmcnt drained before barrier)

    for (int t = 0; t < 32; t++) {
        int cur = t & 1;
        if (t < 31) STAGE(cur ^ 1);   // DMA tile t+1; lands by end barrier

        // ---- S = Q K^T (phys col c = kv (c&15)*4+(c>>4) via K row perm) ----
        f32x4 s[4][4];
#pragma unroll
        for (int ct = 0; ct < 4; ct++) {
            int krow = ct * 16 + l15;
            int ksw = (krow & 7) << 3;
            const unsigned short* kb = &Ksh[cur][krow * 64];
            bf16x8 kb0 = *(const bf16x8*)&kb[ko ^ ksw];
            bf16x8 kb1 = *(const bf16x8*)&kb[(32 + ko) ^ ksw];
#pragma unroll
            for (int half = 0; half < 4; half++) {
                f32x4 sa = {};
                sa = __builtin_amdgcn_mfma_f32_16x16x32_bf16(qf[half][0], kb0, sa, 0, 0, 0);
                sa = __builtin_amdgcn_mfma_f32_16x16x32_bf16(qf[half][1], kb1, sa, 0, 0, 0);
                s[half][ct] = sa;
            }
        }

        // ---- no-max softmax: p = expf(s); pack pairs; ds_write_b64 ----
#pragma unroll
        for (int half = 0; half < 4; half++)
#pragma unroll
            for (int r = 0; r < 4; r++) {
                int prow = (w * 64 + half * 16 + 4 * g + r) * 72;
                float p0 = __expf(s[half][0][r]);
                float p1 = __expf(s[half][1][r]);
                float p2 = __expf(s[half][2][r]);
                float p3 = __expf(s[half][3][r]);
                lacc[half][r] += (p0 + p1) + (p2 + p3);
                unsigned int u01, u23;
                asm("v_cvt_pk_bf16_f32 %0, %1, %2" : "=v"(u01) : "v"(p0), "v"(p1));
                asm("v_cvt_pk_bf16_f32 %0, %1, %2" : "=v"(u23) : "v"(p2), "v"(p3));
                uint2v pk; pk.x = u01; pk.y = u23;
                *(uint2v*)&Psh[prow + l15 * 4] = pk;
            }

        // rule-18 intra-wave fence: P is wave-private (wave w owns rows
        // w*64..w*64+63); all this wave's ds_writes complete, no motion across.
        asm volatile("s_waitcnt lgkmcnt(0)" ::: "memory");
        __builtin_amdgcn_sched_barrier(0);

        // ---- O += P V (P identity layout; V columns = true kv) ----
        bf16x8 pa[4][2];
#pragma unroll
        for (int half = 0; half < 4; half++) {
            int parow = (w * 64 + half * 16 + l15) * 72;
            pa[half][0] = *(const bf16x8*)&Psh[parow + ko];
            pa[half][1] = *(const bf16x8*)&Psh[parow + 32 + ko];
        }
        __builtin_amdgcn_s_setprio(1);
#pragma unroll
        for (int ct = 0; ct < 4; ct++) {
            int vrow = ct * 16 + l15;
            int vsw = (vrow & 7) << 3;
            const unsigned short* vb = &Vsh[cur][vrow * 64];
            bf16x8 vb0 = *(const bf16x8*)&vb[ko ^ vsw];
            bf16x8 vb1 = *(const bf16x8*)&vb[(32 + ko) ^ vsw];
#pragma unroll
            for (int half = 0; half < 4; half++) {
                oacc[half][ct] = __builtin_amdgcn_mfma_f32_16x16x32_bf16(pa[half][0], vb0, oacc[half][ct], 0, 0, 0);
                oacc[half][ct] = __builtin_amdgcn_mfma_f32_16x16x32_bf16(pa[half][1], vb1, oacc[half][ct], 0, 0, 0);
            }
        }
        __builtin_amdgcn_s_setprio(0);

        __syncthreads();     // P/V reads done; DMA for t+1 landed
    }
#undef STAGE

    // ---- epilogue: one-time l reduction (within 16-lane group), O/l ----
#pragma unroll
    for (int half = 0; half < 4; half++)
#pragma unroll
        for (int r = 0; r < 4; r++) {
            float lf = lacc[half][r];
#pragma unroll
            for (int off = 8; off; off >>= 1) lf += __shfl_xor(lf, off);
            float inv = 1.0f / lf;
            int srw = q0 + w * 64 + half * 16 + 4 * g + r;
#pragma unroll
            for (int ct = 0; ct < 4; ct++) {
                int d = ct * 16 + l15;
                o_ws[((size_t)(b * 2048 + srw) * 16 + h) * 64 + d] = f2bf_hw(oacc[half][ct][r] * inv);
            }
        }
}

extern "C" void kernel_launch(void* const* d_in, const int* in_sizes, int n_in,
                              void* d_out, int out_size, void* d_ws, size_t ws_size,
                              hipStream_t stream) {
    const float* x      = (const float*)d_in[0];
    const float* w_qkv  = (const float*)d_in[1];
    const float* b_qkv  = (const float*)d_in[2];
    const float* w_proj = (const float*)d_in[3];
    const float* b_proj = (const float*)d_in[4];
    float* out = (float*)d_out;

    char* ws = (char*)d_ws;
    unsigned short* xb  = (unsigned short*)(ws);               // 16.78 MB
    unsigned short* wqt = (unsigned short*)(ws + 16777216);    //  6.29 MB
    unsigned short* wpt = (unsigned short*)(ws + 23068672);    //  2.10 MB
    unsigned short* qw  = (unsigned short*)(ws + 25165824);    // 16.78 MB
    unsigned short* kw  = (unsigned short*)(ws + 41943040);    // 16.78 MB
    unsigned short* vtw = (unsigned short*)(ws + 58720256);    // 16.78 MB
    unsigned short* ow  = (unsigned short*)(ws + 75497472);    // 16.78 MB -> total 92.3 MB

    // fused prep: x->bf16 (blocks 0..4095), w_qkv tpose (4096..7167),
    // w_proj tpose (7168..8191)
    k_prep<<<8192, 256, 0, stream>>>(x, xb, w_qkv, wqt, w_proj, wpt);
    // QKV GEMM + scatter (Q scaled by 0.125)
    k_gemm<1><<<dim3(24, 64), 256, 0, stream>>>(xb, wqt, b_qkv, 8192, 3072, 1024,
                                                nullptr, qw, kw, vtw);
    // attention: 256 q-rows per block
    k_attn<<<dim3(8, 64), 256, 0, stream>>>(qw, kw, vtw, ow);
    // output projection
    k_gemm<0><<<dim3(8, 64), 256, 0, stream>>>(ow, wpt, b_proj, 8192, 1024, 1024,
                                               out, nullptr, nullptr, nullptr);
}

// Round 21
// 207.046 us; speedup vs baseline: 1.1045x; 1.1045x over previous
//
#include <hip/hip_runtime.h>
#include <hip/hip_bf16.h>

typedef float f32x4 __attribute__((ext_vector_type(4)));
typedef short bf16x8 __attribute__((ext_vector_type(8)));
typedef unsigned short ushort8 __attribute__((ext_vector_type(8)));
typedef unsigned int uint2v __attribute__((ext_vector_type(2)));

__device__ __forceinline__ unsigned short f2bf(float f) {
    union { float f; unsigned u; } v; v.f = f;
    unsigned r = v.u + 0x7fffu + ((v.u >> 16) & 1u);
    return (unsigned short)(r >> 16);
}

// official HIP bf16 conversion (RNE, HW cvt) — used in k_attn epilogue
__device__ __forceinline__ unsigned short f2bf_hw(float f) {
    union { __hip_bfloat16 b; unsigned short u; } cv;
    cv.b = __float2bfloat16(f);
    return cv.u;
}

#define GLDS16(g, l)                                                        \
    __builtin_amdgcn_global_load_lds(                                       \
        (const __attribute__((address_space(1))) unsigned int*)(const void*)(g), \
        (__attribute__((address_space(3))) unsigned int*)(void*)(l), 16, 0, 0)

// ------------- fused prep: x fp32->bf16 + both weight transposes -------
__global__ __launch_bounds__(256) void k_prep(const float* __restrict__ x,
                                              unsigned short* __restrict__ xb,
                                              const float* __restrict__ wq,
                                              unsigned short* __restrict__ wqt,
                                              const float* __restrict__ wp,
                                              unsigned short* __restrict__ wpt) {
    __shared__ float t[32][33];
    int bid = blockIdx.x, tid = threadIdx.x;
    if (bid < 4096) {
        int i = bid * 256 + tid;
        float4 a = ((const float4*)x)[i * 2];
        float4 b = ((const float4*)x)[i * 2 + 1];
        ushort8 o = { f2bf(a.x), f2bf(a.y), f2bf(a.z), f2bf(a.w),
                      f2bf(b.x), f2bf(b.y), f2bf(b.z), f2bf(b.w) };
        ((ushort8*)xb)[i] = o;
        return;
    }
    const float* in; unsigned short* out; int C, c0, r0;
    const int R = 1024;
    if (bid < 7168) {
        int bx = bid - 4096; in = wq; out = wqt; C = 3072;
        c0 = (bx % 96) * 32; r0 = (bx / 96) * 32;
    } else {
        int bx = bid - 7168; in = wp; out = wpt; C = 1024;
        c0 = (bx & 31) * 32; r0 = (bx >> 5) * 32;
    }
    int tx = tid & 31, ty = tid >> 5;
#pragma unroll
    for (int i = 0; i < 4; i++)
        t[ty + i * 8][tx] = in[(size_t)(r0 + ty + i * 8) * C + c0 + tx];
    __syncthreads();
#pragma unroll
    for (int i = 0; i < 4; i++)
        out[(size_t)(c0 + ty + i * 8) * R + r0 + tx] = f2bf(t[tx][ty + i * 8]);
}

// ---------------- GEMM: C[M,N] = A[M,K](bf16) * Bt[N,K](bf16)^T --------
// r19-VERIFIED: double-buffered GLDS prefetch, BK=32, ONE barrier/K-step.
// MODE 0: out fp32 row-major + bias.
// MODE 1: QKV scatter: Q (x0.125)/K direct; V via two-pass LDS transpose.
template <int MODE>
__global__ __launch_bounds__(256)
void k_gemm(const unsigned short* __restrict__ A, const unsigned short* __restrict__ Bt,
            const float* __restrict__ bias, int M, int N, int K,
            float* __restrict__ outF, unsigned short* __restrict__ q_ws,
            unsigned short* __restrict__ k_ws, unsigned short* __restrict__ vt_ws) {
    __shared__ __attribute__((aligned(16))) unsigned short SMEM[16384];  // 32 KB
    int tid = threadIdx.x;
    int lane = tid & 63, w = tid >> 6;
    int wr = w >> 1, wc = w & 1;

    // T1 XCD-aware chunked swizzle (bijective: grid counts are multiples of 8)
    int nbx = gridDim.x;
    int flat = blockIdx.y * nbx + blockIdx.x;
    int cpx = (nbx * gridDim.y) >> 3;
    int wg = (flat & 7) * cpx + (flat >> 3);
    int m0 = (wg / nbx) * 128, n0 = (wg % nbx) * 128;

    f32x4 acc[4][4] = {};

    int srow = tid >> 2, sk = (tid & 3) * 8;
    const unsigned short* aS0 = A + (size_t)(m0 + srow) * K + sk;
    const unsigned short* aS1 = A + (size_t)(m0 + 64 + srow) * K + sk;
    const unsigned short* bS0 = Bt + (size_t)(n0 + srow) * K + sk;
    const unsigned short* bS1 = Bt + (size_t)(n0 + 64 + srow) * K + sk;
    int wb = w * 512;   // wave-uniform dest base (shorts)

    int ko = (lane >> 4) * 8;
    int l15g = lane & 15;
    int arow = (wr * 64 + l15g) * 32;
    int brow = (wc * 64 + l15g) * 32;

#define GSTAGE(BUF)                                                            \
    {                                                                          \
        GLDS16(aS0, SMEM + (BUF) * 4096 + wb);                                 \
        GLDS16(aS1, SMEM + (BUF) * 4096 + 2048 + wb);                          \
        GLDS16(bS0, SMEM + 8192 + (BUF) * 4096 + wb);                          \
        GLDS16(bS1, SMEM + 8192 + (BUF) * 4096 + 2048 + wb);                   \
        aS0 += 32; aS1 += 32; bS0 += 32; bS1 += 32;                            \
    }

    GSTAGE(0);
    __syncthreads();   // prologue: tile 0 landed

    int nt = K >> 5;
    for (int t = 0; t < nt; t++) {
        int cur = t & 1;
        if (t + 1 < nt) GSTAGE(cur ^ 1);   // DMA next tile; overlaps compute
        const unsigned short* Ab = SMEM + cur * 4096;
        const unsigned short* Bb = SMEM + 8192 + cur * 4096;
        bf16x8 af[4], bfr[4];
#pragma unroll
        for (int i = 0; i < 4; i++) {
            af[i]  = *(const bf16x8*)&Ab[arow + i * 512 + ko];
            bfr[i] = *(const bf16x8*)&Bb[brow + i * 512 + ko];
        }
#pragma unroll
        for (int i = 0; i < 4; i++)
#pragma unroll
            for (int j = 0; j < 4; j++)
                acc[i][j] = __builtin_amdgcn_mfma_f32_16x16x32_bf16(af[i], bfr[j], acc[i][j], 0, 0, 0);
        __syncthreads();   // reads done + next-tile DMA landed
    }
#undef GSTAGE

    int colBase = n0 + wc * 64 + l15g;
    int rowBase = m0 + wr * 64 + ((lane >> 4) << 2);

    if constexpr (MODE == 1) {
        if (n0 >= 2048) {
            // ---- V: two-pass transpose via LDS [64][136] (aliases staging) ----
            unsigned short* Vt = SMEM;
            int rowrd = tid >> 2;
#pragma unroll
            for (int pass = 0; pass < 2; pass++) {
                __syncthreads();   // prior reads (staging / pass-0 stores) done
                if (wc == pass) {
#pragma unroll
                    for (int i = 0; i < 4; i++)
#pragma unroll
                        for (int j = 0; j < 4; j++)
#pragma unroll
                            for (int r = 0; r < 4; r++) {
                                int nl = j * 16 + l15g;                   // 0..63
                                int ml = wr * 64 + i * 16 + ((lane >> 4) << 2) + r;
                                Vt[nl * 136 + ml] = f2bf(acc[i][j][r] + bias[n0 + pass * 64 + nl]);
                            }
                }
                __syncthreads();
                int rem = (n0 + pass * 64 + rowrd) & 1023;
                unsigned short* dst = vt_ws
                    + ((size_t)((m0 >> 11) * 16 + (rem >> 6)) * 64 + (rem & 63)) * 2048
                    + (m0 & 2047) + (tid & 3) * 32;
                const unsigned short* src = &Vt[rowrd * 136 + (tid & 3) * 32];
#pragma unroll
                for (int q2 = 0; q2 < 4; q2++)
                    ((uint4*)dst)[q2] = ((const uint4*)src)[q2];
            }
            return;
        }
    }

#pragma unroll
    for (int i = 0; i < 4; i++)
#pragma unroll
        for (int j = 0; j < 4; j++)
#pragma unroll
            for (int r = 0; r < 4; r++) {
                int m = rowBase + i * 16 + r;
                int n = colBase + j * 16;
                float v = acc[i][j][r] + bias[n];
                if constexpr (MODE == 0) {
                    outF[(size_t)m * N + n] = v;
                } else {
                    int which = n >> 10, rem = n & 1023;
                    int h = rem >> 6, d = rem & 63;
                    int b = m >> 11, s = m & 2047;
                    int bh = b * 16 + h;
                    if (which == 0)
                        q_ws[((size_t)bh * 2048 + s) * 64 + d] = f2bf(v * 0.125f);
                    else
                        k_ws[((size_t)bh * 2048 + s) * 64 + d] = f2bf(v);
                }
            }
}

// ---------------- flash attention: per (bh, 128 q-rows) ----------------
// r17/r18/r19-VERIFIED template (112.9 us), byte-identical.
__global__ __launch_bounds__(256)
void k_attn(const unsigned short* __restrict__ q_ws, const unsigned short* __restrict__ k_ws,
            const unsigned short* __restrict__ vt_ws, unsigned short* __restrict__ o_ws) {
    __shared__ __attribute__((aligned(16))) unsigned short Ksh[2][64 * 64];
    __shared__ __attribute__((aligned(16))) unsigned short Vsh[2][64 * 64];
    __shared__ __attribute__((aligned(16))) unsigned short Psh[128 * 72];
    int tid = threadIdx.x, lane = tid & 63, w = tid >> 6;
    int l15 = lane & 15, g = lane >> 4;

    // T1 swizzle: flat 1024 blocks -> XCD chunks of 128 (8 bh per XCD)
    int flat = blockIdx.y * 16 + blockIdx.x;
    int wg = (flat & 7) * 128 + (flat >> 3);
    int bh = wg >> 4;
    int q0 = (wg & 15) * 128;
    int b = bh >> 4, h = bh & 15;

    const unsigned short* qp = q_ws + (size_t)bh * 2048 * 64;
    const unsigned short* kp = k_ws + (size_t)bh * 2048 * 64;
    const unsigned short* vp = vt_ws + (size_t)bh * 64 * 2048;

    int ko = g * 8;
    // Q fragments (A-operand): rows q = q0 + w*32 + half*16 + l15
    bf16x8 qf[2][2];
#pragma unroll
    for (int half = 0; half < 2; half++) {
        const unsigned short* qr = qp + (size_t)(q0 + w * 32 + half * 16 + l15) * 64;
        qf[half][0] = *(const bf16x8*)(qr + ko);
        qf[half][1] = *(const bf16x8*)(qr + 32 + ko);
    }

    f32x4 oacc[2][4] = {};
    float lacc[2][4] = {};

    // GLDS staging geometry: swizzle + K row-perm applied to SOURCE address
    int srow8 = tid >> 3;                       // 0..31
    int scol = ((tid & 7) ^ (srow8 & 7)) * 8;   // XOR-swizzled source chunk
    int kv0 = (srow8 & 15) * 4 + (srow8 >> 4);  // K row-perm for phys row srow8
    const unsigned short* kN0 = kp + (size_t)kv0 * 64 + scol;
    const unsigned short* kN1 = kp + (size_t)(kv0 + 2) * 64 + scol;
    const unsigned short* vN0 = vp + (size_t)srow8 * 2048 + scol;
    const unsigned short* vN1 = vp + (size_t)(srow8 + 32) * 2048 + scol;

#define STAGE(BUF)                                                             \
    {                                                                          \
        GLDS16(kN0, &Ksh[BUF][w * 512]);                                       \
        GLDS16(kN1, &Ksh[BUF][2048 + w * 512]);                                \
        GLDS16(vN0, &Vsh[BUF][w * 512]);                                       \
        GLDS16(vN1, &Vsh[BUF][2048 + w * 512]);                                \
        kN0 += 4096; kN1 += 4096; vN0 += 64; vN1 += 64;                        \
    }

    STAGE(0);
    __syncthreads();   // prologue DMA landed (vmcnt drained before barrier)

    for (int t = 0; t < 32; t++) {
        int cur = t & 1;
        if (t < 31) STAGE(cur ^ 1);   // DMA tile t+1; lands by barrier [C]

        // ---- S = Q K^T (phys col c = kv (c&15)*4+(c>>4) via K row perm) ----
        f32x4 s[2][4];
#pragma unroll
        for (int ct = 0; ct < 4; ct++) {
            int krow = ct * 16 + l15;
            int ksw = (krow & 7) << 3;
            const unsigned short* kb = &Ksh[cur][krow * 64];
            bf16x8 kb0 = *(const bf16x8*)&kb[ko ^ ksw];
            bf16x8 kb1 = *(const bf16x8*)&kb[(32 + ko) ^ ksw];
#pragma unroll
            for (int half = 0; half < 2; half++) {
                f32x4 sa = {};
                sa = __builtin_amdgcn_mfma_f32_16x16x32_bf16(qf[half][0], kb0, sa, 0, 0, 0);
                sa = __builtin_amdgcn_mfma_f32_16x16x32_bf16(qf[half][1], kb1, sa, 0, 0, 0);
                s[half][ct] = sa;
            }
        }

        // ---- no-max softmax: p = expf(s); pack pairs; ds_write_b64 ----
#pragma unroll
        for (int half = 0; half < 2; half++)
#pragma unroll
            for (int r = 0; r < 4; r++) {
                int prow = (w * 32 + half * 16 + 4 * g + r) * 72;
                float p0 = __expf(s[half][0][r]);
                float p1 = __expf(s[half][1][r]);
                float p2 = __expf(s[half][2][r]);
                float p3 = __expf(s[half][3][r]);
                lacc[half][r] += (p0 + p1) + (p2 + p3);
                unsigned int u01, u23;
                asm("v_cvt_pk_bf16_f32 %0, %1, %2" : "=v"(u01) : "v"(p0), "v"(p1));
                asm("v_cvt_pk_bf16_f32 %0, %1, %2" : "=v"(u23) : "v"(p2), "v"(p3));
                uint2v pk; pk.x = u01; pk.y = u23;
                *(uint2v*)&Psh[prow + l15 * 4] = pk;
            }

        // rule-18 intra-wave fence: P is wave-private; all this wave's
        // ds_writes complete, and no compiler motion across this point.
        asm volatile("s_waitcnt lgkmcnt(0)" ::: "memory");
        __builtin_amdgcn_sched_barrier(0);

        // ---- O += P V (P identity layout; V columns = true kv) ----
        bf16x8 pa[2][2];
#pragma unroll
        for (int half = 0; half < 2; half++) {
            int parow = (w * 32 + half * 16 + l15) * 72;
            pa[half][0] = *(const bf16x8*)&Psh[parow + ko];
            pa[half][1] = *(const bf16x8*)&Psh[parow + 32 + ko];
        }
        __builtin_amdgcn_s_setprio(1);
#pragma unroll
        for (int ct = 0; ct < 4; ct++) {
            int vrow = ct * 16 + l15;
            int vsw = (vrow & 7) << 3;
            const unsigned short* vb = &Vsh[cur][vrow * 64];
            bf16x8 vb0 = *(const bf16x8*)&vb[ko ^ vsw];
            bf16x8 vb1 = *(const bf16x8*)&vb[(32 + ko) ^ vsw];
#pragma unroll
            for (int half = 0; half < 2; half++) {
                oacc[half][ct] = __builtin_amdgcn_mfma_f32_16x16x32_bf16(pa[half][0], vb0, oacc[half][ct], 0, 0, 0);
                oacc[half][ct] = __builtin_amdgcn_mfma_f32_16x16x32_bf16(pa[half][1], vb1, oacc[half][ct], 0, 0, 0);
            }
        }
        __builtin_amdgcn_s_setprio(0);

        __syncthreads();     // [C] P/V reads done; DMA for t+1 landed
    }
#undef STAGE

    // ---- epilogue: one-time l reduction (within 16-lane group), O/l ----
#pragma unroll
    for (int half = 0; half < 2; half++)
#pragma unroll
        for (int r = 0; r < 4; r++) {
            float lf = lacc[half][r];
#pragma unroll
            for (int off = 8; off; off >>= 1) lf += __shfl_xor(lf, off);
            float inv = 1.0f / lf;
            int srw = q0 + w * 32 + half * 16 + 4 * g + r;
#pragma unroll
            for (int ct = 0; ct < 4; ct++) {
                int d = ct * 16 + l15;
                o_ws[((size_t)(b * 2048 + srw) * 16 + h) * 64 + d] = f2bf_hw(oacc[half][ct][r] * inv);
            }
        }
}

extern "C" void kernel_launch(void* const* d_in, const int* in_sizes, int n_in,
                              void* d_out, int out_size, void* d_ws, size_t ws_size,
                              hipStream_t stream) {
    const float* x      = (const float*)d_in[0];
    const float* w_qkv  = (const float*)d_in[1];
    const float* b_qkv  = (const float*)d_in[2];
    const float* w_proj = (const float*)d_in[3];
    const float* b_proj = (const float*)d_in[4];
    float* out = (float*)d_out;

    char* ws = (char*)d_ws;
    unsigned short* xb  = (unsigned short*)(ws);               // 16.78 MB
    unsigned short* wqt = (unsigned short*)(ws + 16777216);    //  6.29 MB
    unsigned short* wpt = (unsigned short*)(ws + 23068672);    //  2.10 MB
    unsigned short* qw  = (unsigned short*)(ws + 25165824);    // 16.78 MB
    unsigned short* kw  = (unsigned short*)(ws + 41943040);    // 16.78 MB
    unsigned short* vtw = (unsigned short*)(ws + 58720256);    // 16.78 MB
    unsigned short* ow  = (unsigned short*)(ws + 75497472);    // 16.78 MB -> total 92.3 MB

    // fused prep: x->bf16 (blocks 0..4095), w_qkv tpose (4096..7167),
    // w_proj tpose (7168..8191)
    k_prep<<<8192, 256, 0, stream>>>(x, xb, w_qkv, wqt, w_proj, wpt);
    // QKV GEMM + scatter (Q scaled by 0.125)
    k_gemm<1><<<dim3(24, 64), 256, 0, stream>>>(xb, wqt, b_qkv, 8192, 3072, 1024,
                                                nullptr, qw, kw, vtw);
    // attention: 128 q-rows per block
    k_attn<<<dim3(16, 64), 256, 0, stream>>>(qw, kw, vtw, ow);
    // output projection
    k_gemm<0><<<dim3(8, 64), 256, 0, stream>>>(ow, wpt, b_proj, 8192, 1024, 1024,
                                               out, nullptr, nullptr, nullptr);
}